// Round 15
// baseline (830.629 us; speedup 1.0000x reference)
//
#include <hip/hip_runtime.h>
#include <hip/hip_bf16.h>

typedef __hip_bfloat16 bf16;
typedef __bf16 v8bf __attribute__((ext_vector_type(8)));
typedef float f32x4 __attribute__((ext_vector_type(4)));
typedef unsigned int v4u __attribute__((ext_vector_type(4)));

constexpr int N = 20000, M = 1024, E = 640000, D = 256;
constexpr size_t SEGEL = (size_t)N * D;
constexpr int NCHUNK = 10000;
constexpr int NSLICE = 128;         // R23: countP/fill at 3 blocks/CU
constexpr int ESLICE = E / NSLICE;  // 5000

__device__ __forceinline__ float b2f(bf16 v) { return __bfloat162float(v); }
__device__ __forceinline__ bf16 f2b(float f) { return __float2bfloat16(f); }
__device__ __forceinline__ float u2f(unsigned short u) { return __uint_as_float(((unsigned)u) << 16); }
__device__ __forceinline__ unsigned short f2u(float f) { bf16 h = __float2bfloat16(f); return *(unsigned short*)&h; }
__device__ __forceinline__ float loadf(const void* p, size_t i, int isbf) {
    return isbf ? b2f(((const bf16*)p)[i]) : ((const float*)p)[i];
}
// R20: inline dtype detection — wave-cooperative ballot over ea[0..63] (L2-hot).
__device__ __forceinline__ int detect_bf(const void* ea) {
    int lane = threadIdx.x & 63;
    float f = u2f(((const unsigned short*)ea)[lane]);
    bool ok = (f >= 0.05f && f <= 1.05f);
    return __popcll(__ballot(ok)) >= 60;
}
__device__ __forceinline__ void fma8(float* acc, uint4 v, float w) {
    acc[0] = fmaf(w, u2f((unsigned short)(v.x & 0xffffu)), acc[0]);
    acc[1] = fmaf(w, u2f((unsigned short)(v.x >> 16)), acc[1]);
    acc[2] = fmaf(w, u2f((unsigned short)(v.y & 0xffffu)), acc[2]);
    acc[3] = fmaf(w, u2f((unsigned short)(v.y >> 16)), acc[3]);
    acc[4] = fmaf(w, u2f((unsigned short)(v.z & 0xffffu)), acc[4]);
    acc[5] = fmaf(w, u2f((unsigned short)(v.z >> 16)), acc[5]);
    acc[6] = fmaf(w, u2f((unsigned short)(v.w & 0xffffu)), acc[6]);
    acc[7] = fmaf(w, u2f((unsigned short)(v.w >> 16)), acc[7]);
}
__device__ __forceinline__ void add8(float* a, uint4 v) {
    a[0] += u2f((unsigned short)(v.x & 0xffffu));
    a[1] += u2f((unsigned short)(v.x >> 16));
    a[2] += u2f((unsigned short)(v.y & 0xffffu));
    a[3] += u2f((unsigned short)(v.y >> 16));
    a[4] += u2f((unsigned short)(v.z & 0xffffu));
    a[5] += u2f((unsigned short)(v.z >> 16));
    a[6] += u2f((unsigned short)(v.w & 0xffffu));
    a[7] += u2f((unsigned short)(v.w >> 16));
}
__device__ __forceinline__ unsigned pack2(float a, float b) {
    return (unsigned)f2u(a) | ((unsigned)f2u(b) << 16);
}

// ---------------------------------------------------------------------------
// Merged weight-transpose (blocks 0..2303, fragment-swizzled WT per R21)
// + col-emb MLP table (2304..3327).
__global__ __launch_bounds__(256) void prep_kernel(
    const void* __restrict__ W0, const void* __restrict__ W1, const void* __restrict__ W2,
    const void* __restrict__ pW1, const void* __restrict__ pb1,
    const void* __restrict__ pW2, const void* __restrict__ pb2,
    bf16* __restrict__ WT, bf16* __restrict__ cemb, const void* __restrict__ ea0)
{
    int isbf = detect_bf(ea0);
    int b = blockIdx.x;
    if (b < 2304) {
        int mat = b >> 8, n = b & 255, k = threadIdx.x;
        const void* W = (mat < 3) ? W0 : (mat < 6) ? W1 : W2;
        int lm = mat - (mat < 3 ? 0 : (mat < 6 ? 3 : 6));
        size_t idx = (size_t)mat * 65536 + (size_t)(n >> 4) * 4096 + (size_t)(k >> 5) * 512
                   + (size_t)((n & 15) + 16 * ((k >> 3) & 3)) * 8 + (k & 7);
        WT[idx] = f2b(loadf(W, (size_t)lm * 65536 + k * 256 + n, isbf));
    } else {
        int j = b - 2304;           // 0..1023
        int d = threadIdx.x;
        float jf = (float)j;
        float acc = loadf(pb2, d, isbf);
        #pragma unroll
        for (int k = 0; k < 16; k++) {
            float h = fmaxf(jf * loadf(pW1, k, isbf) + loadf(pb1, k, isbf), 0.0f);
            acc += h * loadf(pW2, k * 256 + d, isbf);
        }
        cemb[(size_t)j * 256 + d] = f2b(acc);
    }
}

// ---------------------------------------------------------------------------
// x0[i] = mean_{j: init[i][j]!=0} cemb[j]  — wave per node, sparse gather.
__global__ __launch_bounds__(256) void projection_kernel(
    const void* __restrict__ init, const bf16* __restrict__ cemb,
    bf16* __restrict__ x0, const void* __restrict__ ea0)
{
    __shared__ unsigned short idxs[4][1024];
    int isbf = detect_bf(ea0);
    int wave = threadIdx.x >> 6, lane = threadIdx.x & 63;
    int i = blockIdx.x * 4 + wave;
    unsigned long long below = (lane == 63) ? 0x7fffffffffffffffull
                                            : ((1ull << lane) - 1ull);
    int cnt = 0;
    if (isbf) {
        const unsigned short* row = (const unsigned short*)init + (size_t)i * 1024;
        for (int c0 = 0; c0 < 1024; c0 += 64) {
            bool nz = (row[c0 + lane] & 0x7fffu) != 0;
            unsigned long long m = __ballot(nz);
            if (nz) idxs[wave][cnt + __popcll(m & below)] = (unsigned short)(c0 + lane);
            cnt += __popcll(m);
        }
    } else {
        const float* row = (const float*)init + (size_t)i * 1024;
        for (int c0 = 0; c0 < 1024; c0 += 64) {
            bool nz = row[c0 + lane] != 0.0f;
            unsigned long long m = __ballot(nz);
            if (nz) idxs[wave][cnt + __popcll(m & below)] = (unsigned short)(c0 + lane);
            cnt += __popcll(m);
        }
    }
    const uint4* cr4 = (const uint4*)cemb;    // 32 uint4 per 256-elem row
    int L = lane & 31, h = lane >> 5;
    float acc[8] = {0.f, 0.f, 0.f, 0.f, 0.f, 0.f, 0.f, 0.f};
    int npair = cnt >> 1;
    int t = 0;
    for (; t + 8 <= npair; t += 8) {
        uint4 v0 = cr4[(size_t)idxs[wave][2 * (t + 0) + h] * 32 + L];
        uint4 v1 = cr4[(size_t)idxs[wave][2 * (t + 1) + h] * 32 + L];
        uint4 v2 = cr4[(size_t)idxs[wave][2 * (t + 2) + h] * 32 + L];
        uint4 v3 = cr4[(size_t)idxs[wave][2 * (t + 3) + h] * 32 + L];
        uint4 v4 = cr4[(size_t)idxs[wave][2 * (t + 4) + h] * 32 + L];
        uint4 v5 = cr4[(size_t)idxs[wave][2 * (t + 5) + h] * 32 + L];
        uint4 v6 = cr4[(size_t)idxs[wave][2 * (t + 6) + h] * 32 + L];
        uint4 v7 = cr4[(size_t)idxs[wave][2 * (t + 7) + h] * 32 + L];
        add8(acc, v0); add8(acc, v1); add8(acc, v2); add8(acc, v3);
        add8(acc, v4); add8(acc, v5); add8(acc, v6); add8(acc, v7);
    }
    for (; t < npair; t++) {
        uint4 v = cr4[(size_t)idxs[wave][2 * t + h] * 32 + L];
        add8(acc, v);
    }
    if ((cnt & 1) && h == 0) {
        uint4 v = cr4[(size_t)idxs[wave][cnt - 1] * 32 + L];
        add8(acc, v);
    }
    #pragma unroll
    for (int j = 0; j < 8; j++) acc[j] += __shfl_xor(acc[j], 32, 64);
    if (h == 0) {
        float rinv = 1.0f / fmaxf((float)cnt, 1.0f);
        v4u o;
        o.x = pack2(acc[0] * rinv, acc[1] * rinv);
        o.y = pack2(acc[2] * rinv, acc[3] * rinv);
        o.z = pack2(acc[4] * rinv, acc[5] * rinv);
        o.w = pack2(acc[6] * rinv, acc[7] * rinv);
        ((v4u*)x0)[(size_t)i * 32 + L] = o;
    }
}

// ---------------------------------------------------------------------------
// Atomic-free CSR build (LDS histogram counting sort), edges packed as int2.
// R14 lesson: never global atomics (R4: 119 MB coherence-point writes).
__global__ __launch_bounds__(256) void countP_kernel(
    const int* __restrict__ e0, const int* __restrict__ e1, const int* __restrict__ e2,
    int* __restrict__ P)
{
    __shared__ int cur[NCHUNK];
    int b = blockIdx.x;
    int pb = b >> 8, rem = b & 255;
    int ck = rem >> 7, s = rem & 127;
    const int* ei = pb == 0 ? e0 : pb == 1 ? e1 : e2;
    int c0 = ck * NCHUNK;
    int t = threadIdx.x;
    for (int i = t; i < NCHUNK; i += 256) cur[i] = 0;
    __syncthreads();
    int ebase = s * ESLICE;
    for (int e = ebase + t; e < ebase + ESLICE; e += 256) {
        int c = ei[E + e];
        if (c >= c0 && c < c0 + NCHUNK) atomicAdd(&cur[c - c0], 1);
    }
    __syncthreads();
    int* Prow = P + ((size_t)(pb * NSLICE + s)) * N + c0;
    for (int i = t; i < NCHUNK; i += 256) Prow[i] = cur[i];
}

__global__ __launch_bounds__(256) void cnt_sum_kernel(
    const int* __restrict__ P, int* __restrict__ cnt)
{
    int id = blockIdx.x * 256 + threadIdx.x;
    if (id >= 3 * N) return;
    int pb = id / N, c = id - pb * N;
    int sum = 0;
    #pragma unroll 8
    for (int s = 0; s < NSLICE; s++)
        sum += P[((size_t)(pb * NSLICE + s)) * N + c];
    cnt[id] = sum;
}

__global__ __launch_bounds__(1024) void scan_kernel(
    const int* __restrict__ cnt, int* __restrict__ col_ptr)
{
    int pb = blockIdx.x;
    int base = pb * E;
    __shared__ int s[1024];
    int t = threadIdx.x;
    const int CH = 20;
    int i0 = t * CH;
    int sum = 0;
    for (int j = 0; j < CH; j++) { int i = i0 + j; if (i < N) sum += cnt[pb * N + i]; }
    s[t] = sum;
    __syncthreads();
    for (int off = 1; off < 1024; off <<= 1) {
        int v = (t >= off) ? s[t - off] : 0;
        __syncthreads();
        s[t] += v;
        __syncthreads();
    }
    int run = base + s[t] - sum;
    for (int j = 0; j < CH; j++) {
        int i = i0 + j;
        if (i < N) {
            col_ptr[pb * (N + 1) + i] = run;
            run += cnt[pb * N + i];
        }
    }
    if (t == 0) col_ptr[pb * (N + 1) + N] = base + E;
}

__global__ __launch_bounds__(256) void base_kernel(
    int* __restrict__ P, const int* __restrict__ col_ptr)
{
    int id = blockIdx.x * 256 + threadIdx.x;
    if (id >= 3 * N) return;
    int pb = id / N, c = id - pb * N;
    int run = col_ptr[pb * (N + 1) + c];
    for (int s = 0; s < NSLICE; s++) {
        size_t idx = ((size_t)(pb * NSLICE + s)) * N + c;
        int v = P[idx];
        P[idx] = run;
        run += v;
    }
}

// epack[pos] = (row, raw weight bits)
__global__ __launch_bounds__(256) void fill_kernel(
    const int* __restrict__ e0, const int* __restrict__ e1, const int* __restrict__ e2,
    const void* __restrict__ a0, const void* __restrict__ a1, const void* __restrict__ a2,
    const int* __restrict__ P, int2* __restrict__ epack)
{
    __shared__ int cur[NCHUNK];
    int isbf = detect_bf(a0);
    int b = blockIdx.x;
    int pb = b >> 8, rem = b & 255;
    int ck = rem >> 7, s = rem & 127;
    const int* ei = pb == 0 ? e0 : pb == 1 ? e1 : e2;
    const void* ea = pb == 0 ? a0 : pb == 1 ? a1 : a2;
    int c0 = ck * NCHUNK;
    int t = threadIdx.x;
    const int* Prow = P + ((size_t)(pb * NSLICE + s)) * N + c0;
    for (int i = t; i < NCHUNK; i += 256) cur[i] = Prow[i];
    __syncthreads();
    int ebase = s * ESLICE;
    for (int e = ebase + t; e < ebase + ESLICE; e += 256) {
        int c = ei[E + e];
        if (c >= c0 && c < c0 + NCHUNK) {
            int r = ei[e];
            float w = loadf(ea, e, isbf);
            int pos = atomicAdd(&cur[c - c0], 1);
            int2 v; v.x = r; v.y = __float_as_int(w);
            epack[pos] = v;
        }
    }
}

// deg = 1 + sum(w_raw) -> dinv, nloop  (wave per node; raw fp32 weights)
__global__ __launch_bounds__(256) void degsum_kernel(
    const int* __restrict__ col_ptr, const int2* __restrict__ epack,
    float* __restrict__ dinv, float* __restrict__ nloop)
{
    int wave = threadIdx.x >> 6, lane = threadIdx.x & 63;
    int pb = blockIdx.x / 5000;
    int i = (blockIdx.x - pb * 5000) * 4 + wave;
    int start = col_ptr[pb * (N + 1) + i], end = col_ptr[pb * (N + 1) + i + 1];
    float sum = 0.0f;
    for (int p = start + lane; p < end; p += 64) sum += __int_as_float(epack[p].y);
    for (int off = 1; off < 64; off <<= 1) sum += __shfl_xor(sum, off, 64);
    if (lane == 0) {
        float dg = 1.0f + sum;
        dinv[pb * N + i] = rsqrtf(dg);
        nloop[pb * N + i] = 1.0f / dg;
    }
}

// R18: normalize + sort, then emit COMPRESSED 4B edges: (u16 src | bf16 wnorm).
__global__ __launch_bounds__(256) void snorm_sort_kernel(
    const int* __restrict__ col_ptr, const int2* __restrict__ epack,
    unsigned* __restrict__ epk2, const float* __restrict__ dinv)
{
    int wave = threadIdx.x >> 6, lane = threadIdx.x & 63;
    int pb = blockIdx.x / 5000;
    int i = (blockIdx.x - pb * 5000) * 4 + wave;
    int start = col_ptr[pb * (N + 1) + i], end = col_ptr[pb * (N + 1) + i + 1];
    float dc = dinv[pb * N + i];
    for (int base = start; base < end; base += 64) {
        int n = end - base; n = n < 64 ? n : 64;
        int key = 0x7fffffff, val = 0;
        if (lane < n) {
            int2 v = epack[base + lane];
            key = v.x;
            val = __float_as_int(dc * __int_as_float(v.y) * dinv[pb * N + v.x]);
        }
        #pragma unroll
        for (int k = 2; k <= 64; k <<= 1) {
            #pragma unroll
            for (int j = k >> 1; j > 0; j >>= 1) {
                int pk = __shfl_xor(key, j, 64);
                int pv = __shfl_xor(val, j, 64);
                bool up = (lane & k) == 0;
                bool lower = (lane & j) == 0;
                bool takeMin = (up == lower);
                bool sw = takeMin ? (pk < key) : (pk > key);
                if (sw) { key = pk; val = pv; }
            }
        }
        if (lane < n) {
            epk2[base + lane] = (unsigned)key
                              | ((unsigned)f2u(__int_as_float(val)) << 16);
        }
    }
}

// ---------------------------------------------------------------------------
// Wave-per-node aggregation; half-wave per edge, 16B gathers; 4B compressed
// edges. R24 INSTRUMENTATION: per-branch dispatch (pb passed in, 5000 blocks)
// — known cost ~+13 us launch overhead (R9), traffic-neutral. Drops the
// profile top-5 cutoff to ~31 us so the mid-tier kernels finally rank.
// REVERT to single dispatch next round after reading the map.
__global__ __launch_bounds__(256) void aggregate_kernel(
    const bf16* __restrict__ x, bf16* __restrict__ yb,
    const int* __restrict__ col_ptr, const unsigned* __restrict__ epk2,
    const float* __restrict__ nloop, int pb)
{
    int wave = threadIdx.x >> 6, lane = threadIdx.x & 63;
    int i = blockIdx.x * 4 + wave;
    const uint4* xr = (const uint4*)x;           // 32 uint4 per row
    int L = lane & 31, h = lane >> 5;
    int start = col_ptr[pb * (N + 1) + i], end = col_ptr[pb * (N + 1) + i + 1];
    float nl = nloop[pb * N + i];
    float acc[8];
    {
        uint4 sv = xr[(size_t)i * 32 + L];
        float self = (h == 0) ? nl : 0.0f;
        #pragma unroll
        for (int j = 0; j < 8; j++) acc[j] = 0.0f;
        fma8(acc, sv, self);
    }
    for (int base = start; base < end; base += 64) {
        int n = end - base; n = n < 64 ? n : 64;
        int ev = 0;
        if (lane < n)
            ev = (int)__builtin_nontemporal_load(epk2 + base + lane);
        int pmax = (n + 1) >> 1;                 // wave-uniform pair count
        for (int p0 = 0; p0 < pmax; p0 += 8) {
            int m = pmax - p0; m = m < 8 ? m : 8;   // wave-uniform
            uint4 v[8];
            float w[8];
            #pragma unroll
            for (int k = 0; k < 8; k++) {
                int e = 2 * (p0 + k) + h;        // <= 63 always: shfl-safe
                int ee = __shfl(ev, e, 64);      // lanes >= n hold ev=0 -> row 0, w=+0
                int rj = ee & 0xffff;
                w[k] = u2f((unsigned short)((unsigned)ee >> 16));
                if (k < m) v[k] = xr[(size_t)rj * 32 + L];
            }
            #pragma unroll
            for (int k = 0; k < 8; k++)
                if (k < m) fma8(acc, v[k], w[k]);
        }
    }
    #pragma unroll
    for (int j = 0; j < 8; j++) acc[j] += __shfl_xor(acc[j], 32, 64);
    if (h == 0) {
        v4u o;
        o.x = pack2(acc[0], acc[1]);
        o.y = pack2(acc[2], acc[3]);
        o.z = pack2(acc[4], acc[5]);
        o.w = pack2(acc[6], acc[7]);
        __builtin_nontemporal_store(o,
            (v4u*)yb + (size_t)pb * (SEGEL / 8) + (size_t)i * 32 + L);
    }
}

// ---------------------------------------------------------------------------
// R22: xout = relu(y @ W + b) — LDS-staged A + swizzled coalesced B.
__global__ __launch_bounds__(256) void gemm_relu_kernel(
    const bf16* __restrict__ yb, const bf16* __restrict__ WT, int layer,
    const void* __restrict__ b0, const void* __restrict__ b1, const void* __restrict__ b2,
    bf16* __restrict__ o0, bf16* __restrict__ o1, bf16* __restrict__ o2,
    const void* __restrict__ ea0)
{
    constexpr int BPL = 157;                 // ceil(20000/128)
    __shared__ uint4 atile[4096];            // 64 KB: 128 rows x 32 uint4
    int isbf = detect_bf(ea0);
    int pl = blockIdx.x / BPL, blk = blockIdx.x - pl * BPL;
    const bf16* y = yb + (size_t)pl * SEGEL;
    const v8bf* bswz = reinterpret_cast<const v8bf*>(WT + (size_t)(pl * 3 + layer) * 65536);
    const void* bias = pl == 0 ? b0 : pl == 1 ? b1 : b2;
    bf16* xout = pl == 0 ? o0 : pl == 1 ? o1 : o2;

    int t = threadIdx.x;
    #pragma unroll
    for (int j = 0; j < 16; j++) {
        int lin = j * 256 + t;               // 0..4095
        int r = lin >> 5, k8 = lin & 31;     // row 0..127, 16B-col 0..31
        int gr = blk * 128 + r; gr = gr < N ? gr : N - 1;
        atile[r * 32 + (k8 ^ (r & 7))] =
            ((const uint4*)(y + (size_t)gr * 256))[k8];
    }
    __syncthreads();

    int wave = t >> 6, lane = t & 63;
    int wr = wave >> 1, wn = wave & 1;
    int m0 = blk * 128 + wr * 64;
    int n0 = wn * 128;
    int mrow = lane & 15, q = lane >> 4;

    f32x4 acc[4][8] = {};
    for (int k0 = 0; k0 < 256; k0 += 32) {
        int kq = (k0 >> 3) + q;              // 16B-col index 0..31
        v8bf b[8];
        #pragma unroll
        for (int nt = 0; nt < 8; nt++)
            b[nt] = bswz[(size_t)(wn * 8 + nt) * 512 + (size_t)(k0 >> 5) * 64 + lane];
        #pragma unroll
        for (int rs = 0; rs < 4; rs++) {
            int row = wr * 64 + rs * 16 + mrow;   // local row 0..127
            v8bf a = *(const v8bf*)&atile[row * 32 + (kq ^ (row & 7))];
            #pragma unroll
            for (int nt = 0; nt < 8; nt++)
                acc[rs][nt] = __builtin_amdgcn_mfma_f32_16x16x32_bf16(a, b[nt], acc[rs][nt], 0, 0, 0);
        }
    }
    #pragma unroll
    for (int nt = 0; nt < 8; nt++) {
        int col = n0 + nt * 16 + mrow;
        float bv = loadf(bias, (size_t)layer * 256 + col, isbf);
        #pragma unroll
        for (int rs = 0; rs < 4; rs++) {
            #pragma unroll
            for (int r = 0; r < 4; r++) {
                int row = m0 + rs * 16 + q * 4 + r;
                if (row < N)
                    xout[(size_t)row * 256 + col] = f2b(fmaxf(acc[rs][nt][r] + bv, 0.0f));
            }
        }
    }
}

// ---------------------------------------------------------------------------
// Meta-path attention (R0 proven form — never appeared in any top-5).
__global__ __launch_bounds__(256) void attention_kernel(
    const bf16* __restrict__ e0, const bf16* __restrict__ e1, const bf16* __restrict__ e2,
    const void* __restrict__ w_att, void* __restrict__ out, int n_nodes,
    const void* __restrict__ ea0)
{
    int isbf = detect_bf(ea0);
    int wave = threadIdx.x >> 6, lane = threadIdx.x & 63;
    int n = blockIdx.x * 4 + wave;
    if (n >= n_nodes) return;
    int d0 = lane * 4;
    float w[4], v0[4], v1[4], v2[4];
    #pragma unroll
    for (int j = 0; j < 4; j++) {
        w[j]  = loadf(w_att, d0 + j, isbf);
        v0[j] = b2f(e0[(size_t)n * 256 + d0 + j]);
        v1[j] = b2f(e1[(size_t)n * 256 + d0 + j]);
        v2[j] = b2f(e2[(size_t)n * 256 + d0 + j]);
    }
    float s0 = 0, s1 = 0, s2 = 0;
    #pragma unroll
    for (int j = 0; j < 4; j++) { s0 += v0[j] * w[j]; s1 += v1[j] * w[j]; s2 += v2[j] * w[j]; }
    for (int off = 1; off < 64; off <<= 1) {
        s0 += __shfl_xor(s0, off, 64);
        s1 += __shfl_xor(s1, off, 64);
        s2 += __shfl_xor(s2, off, 64);
    }
    float m = fmaxf(s0, fmaxf(s1, s2));
    float a0 = expf(s0 - m), a1 = expf(s1 - m), a2 = expf(s2 - m);
    float inv = 1.0f / (a0 + a1 + a2);
    a0 *= inv; a1 *= inv; a2 *= inv;
    #pragma unroll
    for (int j = 0; j < 4; j++) {
        float v = a0 * v0[j] + a1 * v1[j] + a2 * v2[j];
        if (isbf) ((bf16*)out)[(size_t)n * 256 + d0 + j] = f2b(v);
        else      ((float*)out)[(size_t)n * 256 + d0 + j] = v;
    }
}

// ---------------------------------------------------------------------------
extern "C" void kernel_launch(void* const* d_in, const int* in_sizes, int n_in,
                              void* d_out, int out_size, void* d_ws, size_t ws_size,
                              hipStream_t stream)
{
    (void)in_sizes; (void)n_in; (void)out_size; (void)ws_size;

    const void* init = d_in[0];
    const int*  ei[3] = {(const int*)d_in[1], (const int*)d_in[2], (const int*)d_in[3]};
    const void* ea[3] = {d_in[4], d_in[5], d_in[6]};
    const void* pW1 = d_in[7];
    const void* pb1 = d_in[8];
    const void* pW2 = d_in[9];
    const void* pb2 = d_in[10];
    const void* Wb[3] = {d_in[11], d_in[13], d_in[15]};
    const void* bb[3] = {d_in[12], d_in[14], d_in[16]};
    const void* w_att = d_in[17];

    char* ws = (char*)d_ws;
    size_t off = 0;
    auto carve = [&](size_t bytes) -> char* {
        off = (off + 255) & ~(size_t)255;
        char* p = ws + off; off += bytes; return p;
    };
    bf16*  WT    = (bf16*)carve((size_t)9 * 65536 * 2);
    bf16*  cemb  = (bf16*)carve((size_t)M * D * 2);
    bf16*  x0    = (bf16*)carve(SEGEL * 2);
    int*   cnt   = (int*)carve((size_t)3 * N * 4);
    int*   colp  = (int*)carve((size_t)3 * (N + 1) * 4);
    float* dinv  = (float*)carve((size_t)3 * N * 4);
    float* nloop = (float*)carve((size_t)3 * N * 4);
    int2*  epack = (int2*)carve((size_t)3 * E * 8);
    unsigned* epk2 = (unsigned*)carve((size_t)3 * E * 4);
    bf16*  ybuf  = (bf16*)carve((size_t)3 * SEGEL * 2);
    bf16*  bufA  = (bf16*)carve((size_t)3 * SEGEL * 2);
    bf16*  bufB  = (bf16*)carve((size_t)3 * SEGEL * 2);
    // P (3*128*20000*4 = 30.72MB) aliases bufB exactly: dead before bufB's
    // first write (layer-1 gemm output)
    int* P = (int*)bufB;

    prep_kernel<<<3328, 256, 0, stream>>>(Wb[0], Wb[1], Wb[2],
                                          pW1, pb1, pW2, pb2, WT, cemb, ea[0]);
    projection_kernel<<<5000, 256, 0, stream>>>(init, cemb, x0, ea[0]);

    countP_kernel<<<3 * 2 * NSLICE, 256, 0, stream>>>(ei[0], ei[1], ei[2], P);
    cnt_sum_kernel<<<(3 * N + 255) / 256, 256, 0, stream>>>(P, cnt);
    scan_kernel<<<3, 1024, 0, stream>>>(cnt, colp);
    base_kernel<<<(3 * N + 255) / 256, 256, 0, stream>>>(P, colp);
    fill_kernel<<<3 * 2 * NSLICE, 256, 0, stream>>>(ei[0], ei[1], ei[2],
                                                    ea[0], ea[1], ea[2], P, epack);
    degsum_kernel<<<15000, 256, 0, stream>>>(colp, epack, dinv, nloop);
    snorm_sort_kernel<<<15000, 256, 0, stream>>>(colp, epack, epk2, dinv);

    const bf16 *i0 = x0, *i1 = x0, *i2 = x0;
    bf16* dsts[3] = {bufA, bufB, bufA};
    for (int l = 0; l < 3; l++) {
        const bf16* xin[3] = {i0, i1, i2};
        for (int pb = 0; pb < 3; pb++)
            aggregate_kernel<<<5000, 256, 0, stream>>>(xin[pb], ybuf, colp, epk2,
                                                       nloop, pb);
        bf16* dst = dsts[l];
        gemm_relu_kernel<<<3 * 157, 256, 0, stream>>>(ybuf, WT, l, bb[0], bb[1], bb[2],
                                                      dst, dst + SEGEL, dst + 2 * SEGEL, ea[0]);
        i0 = dst; i1 = dst + SEGEL; i2 = dst + 2 * SEGEL;
    }
    attention_kernel<<<5000, 256, 0, stream>>>(bufA, bufA + SEGEL, bufA + 2 * SEGEL,
                                               w_att, d_out, N, ea[0]);
}

// Round 16
// 795.934 us; speedup vs baseline: 1.0436x; 1.0436x over previous
//
#include <hip/hip_runtime.h>
#include <hip/hip_bf16.h>

typedef __hip_bfloat16 bf16;
typedef __bf16 v8bf __attribute__((ext_vector_type(8)));
typedef float f32x4 __attribute__((ext_vector_type(4)));
typedef unsigned int v4u __attribute__((ext_vector_type(4)));

constexpr int N = 20000, M = 1024, E = 640000, D = 256;
constexpr size_t SEGEL = (size_t)N * D;
constexpr int NCHUNK = 10000;
constexpr int NSLICE = 128;         // R23: countP/fill at 3 blocks/CU
constexpr int ESLICE = E / NSLICE;  // 5000

__device__ __forceinline__ float b2f(bf16 v) { return __bfloat162float(v); }
__device__ __forceinline__ bf16 f2b(float f) { return __float2bfloat16(f); }
__device__ __forceinline__ float u2f(unsigned short u) { return __uint_as_float(((unsigned)u) << 16); }
__device__ __forceinline__ unsigned short f2u(float f) { bf16 h = __float2bfloat16(f); return *(unsigned short*)&h; }
__device__ __forceinline__ float loadf(const void* p, size_t i, int isbf) {
    return isbf ? b2f(((const bf16*)p)[i]) : ((const float*)p)[i];
}
// R20: inline dtype detection — wave-cooperative ballot over ea[0..63] (L2-hot).
__device__ __forceinline__ int detect_bf(const void* ea) {
    int lane = threadIdx.x & 63;
    float f = u2f(((const unsigned short*)ea)[lane]);
    bool ok = (f >= 0.05f && f <= 1.05f);
    return __popcll(__ballot(ok)) >= 60;
}
__device__ __forceinline__ void fma8(float* acc, uint4 v, float w) {
    acc[0] = fmaf(w, u2f((unsigned short)(v.x & 0xffffu)), acc[0]);
    acc[1] = fmaf(w, u2f((unsigned short)(v.x >> 16)), acc[1]);
    acc[2] = fmaf(w, u2f((unsigned short)(v.y & 0xffffu)), acc[2]);
    acc[3] = fmaf(w, u2f((unsigned short)(v.y >> 16)), acc[3]);
    acc[4] = fmaf(w, u2f((unsigned short)(v.z & 0xffffu)), acc[4]);
    acc[5] = fmaf(w, u2f((unsigned short)(v.z >> 16)), acc[5]);
    acc[6] = fmaf(w, u2f((unsigned short)(v.w & 0xffffu)), acc[6]);
    acc[7] = fmaf(w, u2f((unsigned short)(v.w >> 16)), acc[7]);
}
__device__ __forceinline__ void add8(float* a, uint4 v) {
    a[0] += u2f((unsigned short)(v.x & 0xffffu));
    a[1] += u2f((unsigned short)(v.x >> 16));
    a[2] += u2f((unsigned short)(v.y & 0xffffu));
    a[3] += u2f((unsigned short)(v.y >> 16));
    a[4] += u2f((unsigned short)(v.z & 0xffffu));
    a[5] += u2f((unsigned short)(v.z >> 16));
    a[6] += u2f((unsigned short)(v.w & 0xffffu));
    a[7] += u2f((unsigned short)(v.w >> 16));
}
__device__ __forceinline__ unsigned pack2(float a, float b) {
    return (unsigned)f2u(a) | ((unsigned)f2u(b) << 16);
}

// ---------------------------------------------------------------------------
// Merged weight-transpose (blocks 0..2303, fragment-swizzled WT per R21)
// + col-emb MLP table (2304..3327).
__global__ __launch_bounds__(256) void prep_kernel(
    const void* __restrict__ W0, const void* __restrict__ W1, const void* __restrict__ W2,
    const void* __restrict__ pW1, const void* __restrict__ pb1,
    const void* __restrict__ pW2, const void* __restrict__ pb2,
    bf16* __restrict__ WT, bf16* __restrict__ cemb, const void* __restrict__ ea0)
{
    int isbf = detect_bf(ea0);
    int b = blockIdx.x;
    if (b < 2304) {
        int mat = b >> 8, n = b & 255, k = threadIdx.x;
        const void* W = (mat < 3) ? W0 : (mat < 6) ? W1 : W2;
        int lm = mat - (mat < 3 ? 0 : (mat < 6 ? 3 : 6));
        size_t idx = (size_t)mat * 65536 + (size_t)(n >> 4) * 4096 + (size_t)(k >> 5) * 512
                   + (size_t)((n & 15) + 16 * ((k >> 3) & 3)) * 8 + (k & 7);
        WT[idx] = f2b(loadf(W, (size_t)lm * 65536 + k * 256 + n, isbf));
    } else {
        int j = b - 2304;           // 0..1023
        int d = threadIdx.x;
        float jf = (float)j;
        float acc = loadf(pb2, d, isbf);
        #pragma unroll
        for (int k = 0; k < 16; k++) {
            float h = fmaxf(jf * loadf(pW1, k, isbf) + loadf(pb1, k, isbf), 0.0f);
            acc += h * loadf(pW2, k * 256 + d, isbf);
        }
        cemb[(size_t)j * 256 + d] = f2b(acc);
    }
}

// ---------------------------------------------------------------------------
// x0[i] = mean_{j: init[i][j]!=0} cemb[j]  — wave per node, sparse gather.
// R25: VECTORIZED row scan (R15 profile: projection topped the chart at 65us,
// HBM 10%, VALU 27% -> VMEM-issue-bound on 16 scalar-u16 scan loads/row).
// Now uint4 loads (8 cols/lane, 2 rounds; float4 x4 for f32), per-lane
// nz-mask, 6-shfl wave prefix scan, <=8 LDS index writes. Index ORDER differs
// from scalar version (lane-major per 512-col stripe) — set identical, mean
// commutative. Gather: half-wave uint4 (R13).
__global__ __launch_bounds__(256) void projection_kernel(
    const void* __restrict__ init, const bf16* __restrict__ cemb,
    bf16* __restrict__ x0, const void* __restrict__ ea0)
{
    __shared__ unsigned short idxs[4][1024];
    int isbf = detect_bf(ea0);
    int wave = threadIdx.x >> 6, lane = threadIdx.x & 63;
    int i = blockIdx.x * 4 + wave;
    int cnt = 0;
    if (isbf) {
        const uint4* row = (const uint4*)((const unsigned short*)init + (size_t)i * 1024);
        #pragma unroll
        for (int it = 0; it < 2; it++) {
            uint4 v = row[it * 64 + lane];
            int c0 = it * 512 + lane * 8;
            unsigned nz = 0;
            nz |= ((v.x & 0x00007fffu) != 0) ? 1u   : 0;
            nz |= ((v.x & 0x7fff0000u) != 0) ? 2u   : 0;
            nz |= ((v.y & 0x00007fffu) != 0) ? 4u   : 0;
            nz |= ((v.y & 0x7fff0000u) != 0) ? 8u   : 0;
            nz |= ((v.z & 0x00007fffu) != 0) ? 16u  : 0;
            nz |= ((v.z & 0x7fff0000u) != 0) ? 32u  : 0;
            nz |= ((v.w & 0x00007fffu) != 0) ? 64u  : 0;
            nz |= ((v.w & 0x7fff0000u) != 0) ? 128u : 0;
            int cl = __popc(nz);
            int s = cl;
            #pragma unroll
            for (int off = 1; off < 64; off <<= 1) {
                int tt = __shfl(s, lane - off, 64);
                if (lane >= off) s += tt;
            }
            int o = cnt + s - cl;
            #pragma unroll
            for (int j = 0; j < 8; j++)
                if (nz & (1u << j)) idxs[wave][o++] = (unsigned short)(c0 + j);
            cnt += __shfl(s, 63, 64);
        }
    } else {
        const float4* row = (const float4*)((const float*)init + (size_t)i * 1024);
        #pragma unroll
        for (int it = 0; it < 4; it++) {
            float4 v = row[it * 64 + lane];
            int c0 = it * 256 + lane * 4;
            unsigned nz = 0;
            if (v.x != 0.0f) nz |= 1u;
            if (v.y != 0.0f) nz |= 2u;
            if (v.z != 0.0f) nz |= 4u;
            if (v.w != 0.0f) nz |= 8u;
            int cl = __popc(nz);
            int s = cl;
            #pragma unroll
            for (int off = 1; off < 64; off <<= 1) {
                int tt = __shfl(s, lane - off, 64);
                if (lane >= off) s += tt;
            }
            int o = cnt + s - cl;
            #pragma unroll
            for (int j = 0; j < 4; j++)
                if (nz & (1u << j)) idxs[wave][o++] = (unsigned short)(c0 + j);
            cnt += __shfl(s, 63, 64);
        }
    }
    __syncthreads();
    const uint4* cr4 = (const uint4*)cemb;    // 32 uint4 per 256-elem row
    int L = lane & 31, h = lane >> 5;
    float acc[8] = {0.f, 0.f, 0.f, 0.f, 0.f, 0.f, 0.f, 0.f};
    int npair = cnt >> 1;
    int t = 0;
    for (; t + 8 <= npair; t += 8) {
        uint4 v0 = cr4[(size_t)idxs[wave][2 * (t + 0) + h] * 32 + L];
        uint4 v1 = cr4[(size_t)idxs[wave][2 * (t + 1) + h] * 32 + L];
        uint4 v2 = cr4[(size_t)idxs[wave][2 * (t + 2) + h] * 32 + L];
        uint4 v3 = cr4[(size_t)idxs[wave][2 * (t + 3) + h] * 32 + L];
        uint4 v4 = cr4[(size_t)idxs[wave][2 * (t + 4) + h] * 32 + L];
        uint4 v5 = cr4[(size_t)idxs[wave][2 * (t + 5) + h] * 32 + L];
        uint4 v6 = cr4[(size_t)idxs[wave][2 * (t + 6) + h] * 32 + L];
        uint4 v7 = cr4[(size_t)idxs[wave][2 * (t + 7) + h] * 32 + L];
        add8(acc, v0); add8(acc, v1); add8(acc, v2); add8(acc, v3);
        add8(acc, v4); add8(acc, v5); add8(acc, v6); add8(acc, v7);
    }
    for (; t < npair; t++) {
        uint4 v = cr4[(size_t)idxs[wave][2 * t + h] * 32 + L];
        add8(acc, v);
    }
    if ((cnt & 1) && h == 0) {
        uint4 v = cr4[(size_t)idxs[wave][cnt - 1] * 32 + L];
        add8(acc, v);
    }
    #pragma unroll
    for (int j = 0; j < 8; j++) acc[j] += __shfl_xor(acc[j], 32, 64);
    if (h == 0) {
        float rinv = 1.0f / fmaxf((float)cnt, 1.0f);
        v4u o;
        o.x = pack2(acc[0] * rinv, acc[1] * rinv);
        o.y = pack2(acc[2] * rinv, acc[3] * rinv);
        o.z = pack2(acc[4] * rinv, acc[5] * rinv);
        o.w = pack2(acc[6] * rinv, acc[7] * rinv);
        ((v4u*)x0)[(size_t)i * 32 + L] = o;
    }
}

// ---------------------------------------------------------------------------
// Atomic-free CSR build (LDS histogram counting sort), edges packed as int2.
// R14 lesson: never global atomics (R4: 119 MB coherence-point writes).
__global__ __launch_bounds__(256) void countP_kernel(
    const int* __restrict__ e0, const int* __restrict__ e1, const int* __restrict__ e2,
    int* __restrict__ P)
{
    __shared__ int cur[NCHUNK];
    int b = blockIdx.x;
    int pb = b >> 8, rem = b & 255;
    int ck = rem >> 7, s = rem & 127;
    const int* ei = pb == 0 ? e0 : pb == 1 ? e1 : e2;
    int c0 = ck * NCHUNK;
    int t = threadIdx.x;
    for (int i = t; i < NCHUNK; i += 256) cur[i] = 0;
    __syncthreads();
    int ebase = s * ESLICE;
    for (int e = ebase + t; e < ebase + ESLICE; e += 256) {
        int c = ei[E + e];
        if (c >= c0 && c < c0 + NCHUNK) atomicAdd(&cur[c - c0], 1);
    }
    __syncthreads();
    int* Prow = P + ((size_t)(pb * NSLICE + s)) * N + c0;
    for (int i = t; i < NCHUNK; i += 256) Prow[i] = cur[i];
}

__global__ __launch_bounds__(256) void cnt_sum_kernel(
    const int* __restrict__ P, int* __restrict__ cnt)
{
    int id = blockIdx.x * 256 + threadIdx.x;
    if (id >= 3 * N) return;
    int pb = id / N, c = id - pb * N;
    int sum = 0;
    #pragma unroll 8
    for (int s = 0; s < NSLICE; s++)
        sum += P[((size_t)(pb * NSLICE + s)) * N + c];
    cnt[id] = sum;
}

__global__ __launch_bounds__(1024) void scan_kernel(
    const int* __restrict__ cnt, int* __restrict__ col_ptr)
{
    int pb = blockIdx.x;
    int base = pb * E;
    __shared__ int s[1024];
    int t = threadIdx.x;
    const int CH = 20;
    int i0 = t * CH;
    int sum = 0;
    for (int j = 0; j < CH; j++) { int i = i0 + j; if (i < N) sum += cnt[pb * N + i]; }
    s[t] = sum;
    __syncthreads();
    for (int off = 1; off < 1024; off <<= 1) {
        int v = (t >= off) ? s[t - off] : 0;
        __syncthreads();
        s[t] += v;
        __syncthreads();
    }
    int run = base + s[t] - sum;
    for (int j = 0; j < CH; j++) {
        int i = i0 + j;
        if (i < N) {
            col_ptr[pb * (N + 1) + i] = run;
            run += cnt[pb * N + i];
        }
    }
    if (t == 0) col_ptr[pb * (N + 1) + N] = base + E;
}

__global__ __launch_bounds__(256) void base_kernel(
    int* __restrict__ P, const int* __restrict__ col_ptr)
{
    int id = blockIdx.x * 256 + threadIdx.x;
    if (id >= 3 * N) return;
    int pb = id / N, c = id - pb * N;
    int run = col_ptr[pb * (N + 1) + c];
    for (int s = 0; s < NSLICE; s++) {
        size_t idx = ((size_t)(pb * NSLICE + s)) * N + c;
        int v = P[idx];
        P[idx] = run;
        run += v;
    }
}

// epack[pos] = (row, raw weight bits)
__global__ __launch_bounds__(256) void fill_kernel(
    const int* __restrict__ e0, const int* __restrict__ e1, const int* __restrict__ e2,
    const void* __restrict__ a0, const void* __restrict__ a1, const void* __restrict__ a2,
    const int* __restrict__ P, int2* __restrict__ epack)
{
    __shared__ int cur[NCHUNK];
    int isbf = detect_bf(a0);
    int b = blockIdx.x;
    int pb = b >> 8, rem = b & 255;
    int ck = rem >> 7, s = rem & 127;
    const int* ei = pb == 0 ? e0 : pb == 1 ? e1 : e2;
    const void* ea = pb == 0 ? a0 : pb == 1 ? a1 : a2;
    int c0 = ck * NCHUNK;
    int t = threadIdx.x;
    const int* Prow = P + ((size_t)(pb * NSLICE + s)) * N + c0;
    for (int i = t; i < NCHUNK; i += 256) cur[i] = Prow[i];
    __syncthreads();
    int ebase = s * ESLICE;
    for (int e = ebase + t; e < ebase + ESLICE; e += 256) {
        int c = ei[E + e];
        if (c >= c0 && c < c0 + NCHUNK) {
            int r = ei[e];
            float w = loadf(ea, e, isbf);
            int pos = atomicAdd(&cur[c - c0], 1);
            int2 v; v.x = r; v.y = __float_as_int(w);
            epack[pos] = v;
        }
    }
}

// deg = 1 + sum(w_raw) -> dinv, nloop  (wave per node; raw fp32 weights)
__global__ __launch_bounds__(256) void degsum_kernel(
    const int* __restrict__ col_ptr, const int2* __restrict__ epack,
    float* __restrict__ dinv, float* __restrict__ nloop)
{
    int wave = threadIdx.x >> 6, lane = threadIdx.x & 63;
    int pb = blockIdx.x / 5000;
    int i = (blockIdx.x - pb * 5000) * 4 + wave;
    int start = col_ptr[pb * (N + 1) + i], end = col_ptr[pb * (N + 1) + i + 1];
    float sum = 0.0f;
    for (int p = start + lane; p < end; p += 64) sum += __int_as_float(epack[p].y);
    for (int off = 1; off < 64; off <<= 1) sum += __shfl_xor(sum, off, 64);
    if (lane == 0) {
        float dg = 1.0f + sum;
        dinv[pb * N + i] = rsqrtf(dg);
        nloop[pb * N + i] = 1.0f / dg;
    }
}

// R18: normalize + sort, then emit COMPRESSED 4B edges: (u16 src | bf16 wnorm).
__global__ __launch_bounds__(256) void snorm_sort_kernel(
    const int* __restrict__ col_ptr, const int2* __restrict__ epack,
    unsigned* __restrict__ epk2, const float* __restrict__ dinv)
{
    int wave = threadIdx.x >> 6, lane = threadIdx.x & 63;
    int pb = blockIdx.x / 5000;
    int i = (blockIdx.x - pb * 5000) * 4 + wave;
    int start = col_ptr[pb * (N + 1) + i], end = col_ptr[pb * (N + 1) + i + 1];
    float dc = dinv[pb * N + i];
    for (int base = start; base < end; base += 64) {
        int n = end - base; n = n < 64 ? n : 64;
        int key = 0x7fffffff, val = 0;
        if (lane < n) {
            int2 v = epack[base + lane];
            key = v.x;
            val = __float_as_int(dc * __int_as_float(v.y) * dinv[pb * N + v.x]);
        }
        #pragma unroll
        for (int k = 2; k <= 64; k <<= 1) {
            #pragma unroll
            for (int j = k >> 1; j > 0; j >>= 1) {
                int pk = __shfl_xor(key, j, 64);
                int pv = __shfl_xor(val, j, 64);
                bool up = (lane & k) == 0;
                bool lower = (lane & j) == 0;
                bool takeMin = (up == lower);
                bool sw = takeMin ? (pk < key) : (pk > key);
                if (sw) { key = pk; val = pv; }
            }
        }
        if (lane < n) {
            epk2[base + lane] = (unsigned)key
                              | ((unsigned)f2u(__int_as_float(val)) << 16);
        }
    }
}

// ---------------------------------------------------------------------------
// Wave-per-node aggregation; half-wave per edge, 16B gathers; 4B compressed
// edges. Single combined dispatch (R24 split was instrumentation-only; ~+15us).
// Empirical roofline: ~3.8 TB/s fabric-side, FETCH ~312 MB (compulsory ~291).
__global__ __launch_bounds__(256) void aggregate_kernel(
    const bf16* __restrict__ xi0, const bf16* __restrict__ xi1, const bf16* __restrict__ xi2,
    bf16* __restrict__ yb,
    const int* __restrict__ col_ptr, const unsigned* __restrict__ epk2,
    const float* __restrict__ nloop)
{
    int wave = threadIdx.x >> 6, lane = threadIdx.x & 63;
    int pb = blockIdx.x / 5000;
    int i = (blockIdx.x - pb * 5000) * 4 + wave;
    const bf16* x = pb == 0 ? xi0 : pb == 1 ? xi1 : xi2;
    const uint4* xr = (const uint4*)x;           // 32 uint4 per row
    int L = lane & 31, h = lane >> 5;
    int start = col_ptr[pb * (N + 1) + i], end = col_ptr[pb * (N + 1) + i + 1];
    float nl = nloop[pb * N + i];
    float acc[8];
    {
        uint4 sv = xr[(size_t)i * 32 + L];
        float self = (h == 0) ? nl : 0.0f;
        #pragma unroll
        for (int j = 0; j < 8; j++) acc[j] = 0.0f;
        fma8(acc, sv, self);
    }
    for (int base = start; base < end; base += 64) {
        int n = end - base; n = n < 64 ? n : 64;
        int ev = 0;
        if (lane < n)
            ev = (int)__builtin_nontemporal_load(epk2 + base + lane);
        int pmax = (n + 1) >> 1;                 // wave-uniform pair count
        for (int p0 = 0; p0 < pmax; p0 += 8) {
            int m = pmax - p0; m = m < 8 ? m : 8;   // wave-uniform
            uint4 v[8];
            float w[8];
            #pragma unroll
            for (int k = 0; k < 8; k++) {
                int e = 2 * (p0 + k) + h;        // <= 63 always: shfl-safe
                int ee = __shfl(ev, e, 64);      // lanes >= n hold ev=0 -> row 0, w=+0
                int rj = ee & 0xffff;
                w[k] = u2f((unsigned short)((unsigned)ee >> 16));
                if (k < m) v[k] = xr[(size_t)rj * 32 + L];
            }
            #pragma unroll
            for (int k = 0; k < 8; k++)
                if (k < m) fma8(acc, v[k], w[k]);
        }
    }
    #pragma unroll
    for (int j = 0; j < 8; j++) acc[j] += __shfl_xor(acc[j], 32, 64);
    if (h == 0) {
        v4u o;
        o.x = pack2(acc[0], acc[1]);
        o.y = pack2(acc[2], acc[3]);
        o.z = pack2(acc[4], acc[5]);
        o.w = pack2(acc[6], acc[7]);
        __builtin_nontemporal_store(o,
            (v4u*)yb + (size_t)pb * (SEGEL / 8) + (size_t)i * 32 + L);
    }
}

// ---------------------------------------------------------------------------
// R22: xout = relu(y @ W + b) — LDS-staged A + swizzled coalesced B.
__global__ __launch_bounds__(256) void gemm_relu_kernel(
    const bf16* __restrict__ yb, const bf16* __restrict__ WT, int layer,
    const void* __restrict__ b0, const void* __restrict__ b1, const void* __restrict__ b2,
    bf16* __restrict__ o0, bf16* __restrict__ o1, bf16* __restrict__ o2,
    const void* __restrict__ ea0)
{
    constexpr int BPL = 157;                 // ceil(20000/128)
    __shared__ uint4 atile[4096];            // 64 KB: 128 rows x 32 uint4
    int isbf = detect_bf(ea0);
    int pl = blockIdx.x / BPL, blk = blockIdx.x - pl * BPL;
    const bf16* y = yb + (size_t)pl * SEGEL;
    const v8bf* bswz = reinterpret_cast<const v8bf*>(WT + (size_t)(pl * 3 + layer) * 65536);
    const void* bias = pl == 0 ? b0 : pl == 1 ? b1 : b2;
    bf16* xout = pl == 0 ? o0 : pl == 1 ? o1 : o2;

    int t = threadIdx.x;
    #pragma unroll
    for (int j = 0; j < 16; j++) {
        int lin = j * 256 + t;               // 0..4095
        int r = lin >> 5, k8 = lin & 31;     // row 0..127, 16B-col 0..31
        int gr = blk * 128 + r; gr = gr < N ? gr : N - 1;
        atile[r * 32 + (k8 ^ (r & 7))] =
            ((const uint4*)(y + (size_t)gr * 256))[k8];
    }
    __syncthreads();

    int wave = t >> 6, lane = t & 63;
    int wr = wave >> 1, wn = wave & 1;
    int m0 = blk * 128 + wr * 64;
    int n0 = wn * 128;
    int mrow = lane & 15, q = lane >> 4;

    f32x4 acc[4][8] = {};
    for (int k0 = 0; k0 < 256; k0 += 32) {
        int kq = (k0 >> 3) + q;              // 16B-col index 0..31
        v8bf b[8];
        #pragma unroll
        for (int nt = 0; nt < 8; nt++)
            b[nt] = bswz[(size_t)(wn * 8 + nt) * 512 + (size_t)(k0 >> 5) * 64 + lane];
        #pragma unroll
        for (int rs = 0; rs < 4; rs++) {
            int row = wr * 64 + rs * 16 + mrow;   // local row 0..127
            v8bf a = *(const v8bf*)&atile[row * 32 + (kq ^ (row & 7))];
            #pragma unroll
            for (int nt = 0; nt < 8; nt++)
                acc[rs][nt] = __builtin_amdgcn_mfma_f32_16x16x32_bf16(a, b[nt], acc[rs][nt], 0, 0, 0);
        }
    }
    #pragma unroll
    for (int nt = 0; nt < 8; nt++) {
        int col = n0 + nt * 16 + mrow;
        float bv = loadf(bias, (size_t)layer * 256 + col, isbf);
        #pragma unroll
        for (int rs = 0; rs < 4; rs++) {
            #pragma unroll
            for (int r = 0; r < 4; r++) {
                int row = m0 + rs * 16 + q * 4 + r;
                if (row < N)
                    xout[(size_t)row * 256 + col] = f2b(fmaxf(acc[rs][nt][r] + bv, 0.0f));
            }
        }
    }
}

// ---------------------------------------------------------------------------
// Meta-path attention (R0 proven form — never appeared in any top-5).
__global__ __launch_bounds__(256) void attention_kernel(
    const bf16* __restrict__ e0, const bf16* __restrict__ e1, const bf16* __restrict__ e2,
    const void* __restrict__ w_att, void* __restrict__ out, int n_nodes,
    const void* __restrict__ ea0)
{
    int isbf = detect_bf(ea0);
    int wave = threadIdx.x >> 6, lane = threadIdx.x & 63;
    int n = blockIdx.x * 4 + wave;
    if (n >= n_nodes) return;
    int d0 = lane * 4;
    float w[4], v0[4], v1[4], v2[4];
    #pragma unroll
    for (int j = 0; j < 4; j++) {
        w[j]  = loadf(w_att, d0 + j, isbf);
        v0[j] = b2f(e0[(size_t)n * 256 + d0 + j]);
        v1[j] = b2f(e1[(size_t)n * 256 + d0 + j]);
        v2[j] = b2f(e2[(size_t)n * 256 + d0 + j]);
    }
    float s0 = 0, s1 = 0, s2 = 0;
    #pragma unroll
    for (int j = 0; j < 4; j++) { s0 += v0[j] * w[j]; s1 += v1[j] * w[j]; s2 += v2[j] * w[j]; }
    for (int off = 1; off < 64; off <<= 1) {
        s0 += __shfl_xor(s0, off, 64);
        s1 += __shfl_xor(s1, off, 64);
        s2 += __shfl_xor(s2, off, 64);
    }
    float m = fmaxf(s0, fmaxf(s1, s2));
    float a0 = expf(s0 - m), a1 = expf(s1 - m), a2 = expf(s2 - m);
    float inv = 1.0f / (a0 + a1 + a2);
    a0 *= inv; a1 *= inv; a2 *= inv;
    #pragma unroll
    for (int j = 0; j < 4; j++) {
        float v = a0 * v0[j] + a1 * v1[j] + a2 * v2[j];
        if (isbf) ((bf16*)out)[(size_t)n * 256 + d0 + j] = f2b(v);
        else      ((float*)out)[(size_t)n * 256 + d0 + j] = v;
    }
}

// ---------------------------------------------------------------------------
extern "C" void kernel_launch(void* const* d_in, const int* in_sizes, int n_in,
                              void* d_out, int out_size, void* d_ws, size_t ws_size,
                              hipStream_t stream)
{
    (void)in_sizes; (void)n_in; (void)out_size; (void)ws_size;

    const void* init = d_in[0];
    const int*  ei[3] = {(const int*)d_in[1], (const int*)d_in[2], (const int*)d_in[3]};
    const void* ea[3] = {d_in[4], d_in[5], d_in[6]};
    const void* pW1 = d_in[7];
    const void* pb1 = d_in[8];
    const void* pW2 = d_in[9];
    const void* pb2 = d_in[10];
    const void* Wb[3] = {d_in[11], d_in[13], d_in[15]};
    const void* bb[3] = {d_in[12], d_in[14], d_in[16]};
    const void* w_att = d_in[17];

    char* ws = (char*)d_ws;
    size_t off = 0;
    auto carve = [&](size_t bytes) -> char* {
        off = (off + 255) & ~(size_t)255;
        char* p = ws + off; off += bytes; return p;
    };
    bf16*  WT    = (bf16*)carve((size_t)9 * 65536 * 2);
    bf16*  cemb  = (bf16*)carve((size_t)M * D * 2);
    bf16*  x0    = (bf16*)carve(SEGEL * 2);
    int*   cnt   = (int*)carve((size_t)3 * N * 4);
    int*   colp  = (int*)carve((size_t)3 * (N + 1) * 4);
    float* dinv  = (float*)carve((size_t)3 * N * 4);
    float* nloop = (float*)carve((size_t)3 * N * 4);
    int2*  epack = (int2*)carve((size_t)3 * E * 8);
    unsigned* epk2 = (unsigned*)carve((size_t)3 * E * 4);
    bf16*  ybuf  = (bf16*)carve((size_t)3 * SEGEL * 2);
    bf16*  bufA  = (bf16*)carve((size_t)3 * SEGEL * 2);
    bf16*  bufB  = (bf16*)carve((size_t)3 * SEGEL * 2);
    // P (3*128*20000*4 = 30.72MB) aliases bufB exactly: dead before bufB's
    // first write (layer-1 gemm output)
    int* P = (int*)bufB;

    prep_kernel<<<3328, 256, 0, stream>>>(Wb[0], Wb[1], Wb[2],
                                          pW1, pb1, pW2, pb2, WT, cemb, ea[0]);
    projection_kernel<<<5000, 256, 0, stream>>>(init, cemb, x0, ea[0]);

    countP_kernel<<<3 * 2 * NSLICE, 256, 0, stream>>>(ei[0], ei[1], ei[2], P);
    cnt_sum_kernel<<<(3 * N + 255) / 256, 256, 0, stream>>>(P, cnt);
    scan_kernel<<<3, 1024, 0, stream>>>(cnt, colp);
    base_kernel<<<(3 * N + 255) / 256, 256, 0, stream>>>(P, colp);
    fill_kernel<<<3 * 2 * NSLICE, 256, 0, stream>>>(ei[0], ei[1], ei[2],
                                                    ea[0], ea[1], ea[2], P, epack);
    degsum_kernel<<<15000, 256, 0, stream>>>(colp, epack, dinv, nloop);
    snorm_sort_kernel<<<15000, 256, 0, stream>>>(colp, epack, epk2, dinv);

    const bf16 *i0 = x0, *i1 = x0, *i2 = x0;
    bf16* dsts[3] = {bufA, bufB, bufA};
    for (int l = 0; l < 3; l++) {
        aggregate_kernel<<<15000, 256, 0, stream>>>(i0, i1, i2, ybuf, colp, epk2, nloop);
        bf16* dst = dsts[l];
        gemm_relu_kernel<<<3 * 157, 256, 0, stream>>>(ybuf, WT, l, bb[0], bb[1], bb[2],
                                                      dst, dst + SEGEL, dst + 2 * SEGEL, ea[0]);
        i0 = dst; i1 = dst + SEGEL; i2 = dst + 2 * SEGEL;
    }
    attention_kernel<<<5000, 256, 0, stream>>>(bufA, bufA + SEGEL, bufA + 2 * SEGEL,
                                               w_att, d_out, N, ea[0]);
}